// Round 6
// baseline (105.718 us; speedup 1.0000x reference)
//
#include <hip/hip_runtime.h>
#include <hip/hip_fp16.h>

#define Bn 4
#define Tn 16
#define Nn 50000
#define Cn 16
#define En 50000
#define LAM 0.3f
#define COS_EPS 1e-8f
#define NORM_EPS 1e-8f

// fp16 feature table, BATCH-major: feat[b][n][32] halves -> row (b,n) = 64 B,
// one batch slab = 3.2 MB (fits per-XCD L2). Chunk c4 holds [mu4|sd4] (fixed
// permutation, consistent for member & center -> cosine unchanged).
union H8 { __half2 h2[4]; float4 f4; };

// Kernel 1: thread = (bn, c4); x reads coalesced (1KB/wave), writes fully
// coalesced 16 B chunks (consecutive threads -> consecutive addresses).
// Also re-inits the global min/max cells every launch (replay-safe).
__global__ void feat_kernel(const float* __restrict__ x, float4* __restrict__ feat,
                            unsigned* __restrict__ mm) {
    if (blockIdx.x == 0 && threadIdx.x < 2 * Bn) {
        mm[threadIdx.x] = (threadIdx.x & 1) ? 0u : 0x7F800000u;  // min=+inf, max=0
    }
    int gid = blockIdx.x * blockDim.x + threadIdx.x;
    if (gid >= Bn * Nn * 4) return;
    int c4 = gid & 3;
    int bn = gid >> 2;            // b*N + n  (batch-major row id)
    int b  = bn / Nn;
    int n  = bn - b * Nn;

    const float4* x4 = (const float4*)x;
    float4 s  = make_float4(0.f, 0.f, 0.f, 0.f);
    float4 ss = make_float4(0.f, 0.f, 0.f, 0.f);
    int base = (b * Tn) * Nn;     // row units of 16 floats
#pragma unroll
    for (int t = 0; t < Tn; ++t) {
        float4 v = x4[(base + t * Nn + n) * 4 + c4];
        s.x += v.x; s.y += v.y; s.z += v.z; s.w += v.w;
        ss.x += v.x * v.x; ss.y += v.y * v.y; ss.z += v.z * v.z; ss.w += v.w * v.w;
    }
    const float inv = 1.0f / (float)Tn;
    float4 m, sd;
    m.x = s.x * inv; m.y = s.y * inv; m.z = s.z * inv; m.w = s.w * inv;
    sd.x = sqrtf(fmaxf(ss.x * inv - m.x * m.x, 0.f));
    sd.y = sqrtf(fmaxf(ss.y * inv - m.y * m.y, 0.f));
    sd.z = sqrtf(fmaxf(ss.z * inv - m.z * m.z, 0.f));
    sd.w = sqrtf(fmaxf(ss.w * inv - m.w * m.w, 0.f));

    float p = m.x * m.x + m.y * m.y + m.z * m.z + m.w * m.w
            + sd.x * sd.x + sd.y * sd.y + sd.z * sd.z + sd.w * sd.w;
    p += __shfl_xor(p, 1);
    p += __shfl_xor(p, 2);
    float rn = 1.0f / fmaxf(sqrtf(p), COS_EPS);

    H8 o;
    o.h2[0] = __floats2half2_rn(m.x * rn,  m.y * rn);
    o.h2[1] = __floats2half2_rn(m.z * rn,  m.w * rn);
    o.h2[2] = __floats2half2_rn(sd.x * rn, sd.y * rn);
    o.h2[3] = __floats2half2_rn(sd.z * rn, sd.w * rn);
    feat[(size_t)bn * 4 + c4] = o.f4;     // 16 B chunk, coalesced
}

// Kernel 2: one WAVE per (edge, batch); batch = blockIdx.y so all blocks of a
// batch dispatch together -> each XCD's L2 holds the 3.2 MB batch slab.
// Lane l: g=l>>2 member slot, q=l&3 chunk; member gather = 64 B/group.
__global__ void edge_sim_kernel(const float4* __restrict__ feat,
                                const int* __restrict__ members,
                                const int* __restrict__ centers,
                                const int* __restrict__ offsets,
                                float* __restrict__ ms) {
    int tid  = blockIdx.x * blockDim.x + threadIdx.x;
    int e    = tid >> 6;
    if (e >= En) return;
    int b    = blockIdx.y;
    int lane = threadIdx.x & 63;
    int g    = lane >> 2;
    int q    = lane & 3;

    int off0 = offsets[e];
    int off1 = offsets[e + 1];
    int deg  = off1 - off0;
    int cn   = centers[e];

    const float4* slab = feat + (size_t)b * Nn * 4;

    // center chunk q as floats
    float cf[8];
    {
        H8 u; u.f4 = slab[cn * 4 + q];
#pragma unroll
        for (int i = 0; i < 4; ++i) {
            float2 p = __half22float2(u.h2[i]);
            cf[2 * i]     = p.x;
            cf[2 * i + 1] = p.y;
        }
    }

    float ssum = 0.f;
    for (int m0 = g; m0 < deg; m0 += 16) {
        int mn = members[off0 + m0];
        H8 u; u.f4 = slab[mn * 4 + q];
        float d = 0.f;
#pragma unroll
        for (int i = 0; i < 4; ++i) {
            float2 p = __half22float2(u.h2[i]);
            d += p.x * cf[2 * i] + p.y * cf[2 * i + 1];
        }
        d += __shfl_xor(d, 1);
        d += __shfl_xor(d, 2);        // all 4 lanes of group g hold full 32-dot
        ssum += fminf(fmaxf(d, 0.f), 1.f);
    }
    // reduce across the 16 groups (each q-class holds one copy per group)
    ssum += __shfl_xor(ssum, 4);
    ssum += __shfl_xor(ssum, 8);
    ssum += __shfl_xor(ssum, 16);
    ssum += __shfl_xor(ssum, 32);

    if (lane == 0) ms[b * En + e] = ssum / fmaxf((float)deg, 1.0f);
}

// Kernel 3: per-batch min/max via uint-bit atomics (values >= 0 so uint order
// == float order). 64 blocks per batch, 2 atomics per block (512 total).
__global__ void minmax_kernel(const float* __restrict__ ms, unsigned* __restrict__ mm) {
    int b = blockIdx.x >> 6;
    int j = blockIdx.x & 63;
    const float* p = ms + b * En;
    float lo = INFINITY, hi = 0.f;
    for (int i = j * blockDim.x + threadIdx.x; i < En; i += 64 * 256) {
        float v = p[i];
        lo = fminf(lo, v);
        hi = fmaxf(hi, v);
    }
#pragma unroll
    for (int m = 1; m < 64; m <<= 1) {
        lo = fminf(lo, __shfl_xor(lo, m));
        hi = fmaxf(hi, __shfl_xor(hi, m));
    }
    __shared__ float slo[4], shi[4];
    int wid  = threadIdx.x >> 6;
    int lane = threadIdx.x & 63;
    if (lane == 0) { slo[wid] = lo; shi[wid] = hi; }
    __syncthreads();
    if (threadIdx.x == 0) {
        float flo = fminf(fminf(slo[0], slo[1]), fminf(slo[2], slo[3]));
        float fhi = fmaxf(fmaxf(shi[0], shi[1]), fmaxf(shi[2], shi[3]));
        atomicMin(&mm[b * 2],     __float_as_uint(flo));
        atomicMax(&mm[b * 2 + 1], __float_as_uint(fhi));
    }
}

// Kernel 4: out = W * (1 + LAM * minmax-normed mean_sim)
__global__ void out_kernel(const float* __restrict__ ms, const unsigned* __restrict__ mm,
                           const float* __restrict__ W, float* __restrict__ out) {
    int gid = blockIdx.x * blockDim.x + threadIdx.x;
    if (gid >= Bn * En) return;
    int b = gid / En;
    int e = gid - b * En;
    float smin = __uint_as_float(mm[b * 2]);
    float smax = __uint_as_float(mm[b * 2 + 1]);
    float v = (ms[gid] - smin) / (smax - smin + NORM_EPS);
    out[gid] = W[e] * (1.0f + LAM * v);
}

extern "C" void kernel_launch(void* const* d_in, const int* in_sizes, int n_in,
                              void* d_out, int out_size, void* d_ws, size_t ws_size,
                              hipStream_t stream) {
    const float* x_raw        = (const float*)d_in[0];
    // d_in[1] = H, unused
    const float* W            = (const float*)d_in[2];
    const int*   edge_members = (const int*)d_in[3];
    const int*   edge_centers = (const int*)d_in[4];
    const int*   edge_offsets = (const int*)d_in[5];
    float*       out          = (float*)d_out;

    float4*   feat = (float4*)d_ws;                                 // B*N*64 B = 12.8 MB
    float*    ms   = (float*)((char*)d_ws + (size_t)Bn * Nn * 64);  // B*E floats
    unsigned* mm   = (unsigned*)(ms + (size_t)Bn * En);             // 2*B uints

    {
        int total = Bn * Nn * 4;
        feat_kernel<<<(total + 255) / 256, 256, 0, stream>>>(x_raw, feat, mm);
    }
    {
        // one wave per (edge, batch); y = batch so batches phase through L2
        dim3 grid((unsigned)(((long long)En * 64 + 255) / 256), Bn);
        edge_sim_kernel<<<grid, 256, 0, stream>>>(
            feat, edge_members, edge_centers, edge_offsets, ms);
    }
    minmax_kernel<<<Bn * 64, 256, 0, stream>>>(ms, mm);
    {
        int total = Bn * En;
        out_kernel<<<(total + 255) / 256, 256, 0, stream>>>(ms, mm, W, out);
    }
}

// Round 7
// 77.950 us; speedup vs baseline: 1.3562x; 1.3562x over previous
//
#include <hip/hip_runtime.h>
#include <hip/hip_fp16.h>

#define Bn 4
#define Tn 16
#define Nn 50000
#define Cn 16
#define En 50000
#define LAM 0.3f
#define COS_EPS 1e-8f
#define NORM_EPS 1e-8f

// fp16 feature table, NODE-major: feat[n][b][32] halves -> node row = 256 B,
// fully consumed per member gather by the 4-batch unroll (full-line util).
// Chunk c4 holds [mu4|sd4] (fixed permutation, consistent member & center).
union H8 { __half2 h2[4]; float4 f4; };

// Kernel 1: thread = (n, b, c4)  [b,c4 in low bits since Bn=4]:
//   gid = ((n*4 + b)*4) + c4  ->  writes 16 B chunks, wave = 1 KB contiguous.
// x reads: per t, each b-group of 16 lanes reads 256 B contiguous. Coalesced.
// Also re-inits the global min/max cells every launch (replay-safe).
__global__ void feat_kernel(const float* __restrict__ x, float4* __restrict__ feat,
                            unsigned* __restrict__ mm) {
    if (blockIdx.x == 0 && threadIdx.x < 2 * Bn) {
        mm[threadIdx.x] = (threadIdx.x & 1) ? 0u : 0x7F800000u;  // min=+inf, max=0
    }
    int gid = blockIdx.x * blockDim.x + threadIdx.x;
    if (gid >= Bn * Nn * 4) return;
    int c4 = gid & 3;
    int b  = (gid >> 2) & 3;
    int n  = gid >> 4;

    const float4* x4 = (const float4*)x;
    float4 s  = make_float4(0.f, 0.f, 0.f, 0.f);
    float4 ss = make_float4(0.f, 0.f, 0.f, 0.f);
    int base = (b * Tn) * Nn;     // row units of 16 floats
#pragma unroll
    for (int t = 0; t < Tn; ++t) {
        float4 v = x4[(base + t * Nn + n) * 4 + c4];
        s.x += v.x; s.y += v.y; s.z += v.z; s.w += v.w;
        ss.x += v.x * v.x; ss.y += v.y * v.y; ss.z += v.z * v.z; ss.w += v.w * v.w;
    }
    const float inv = 1.0f / (float)Tn;
    float4 m, sd;
    m.x = s.x * inv; m.y = s.y * inv; m.z = s.z * inv; m.w = s.w * inv;
    sd.x = sqrtf(fmaxf(ss.x * inv - m.x * m.x, 0.f));
    sd.y = sqrtf(fmaxf(ss.y * inv - m.y * m.y, 0.f));
    sd.z = sqrtf(fmaxf(ss.z * inv - m.z * m.z, 0.f));
    sd.w = sqrtf(fmaxf(ss.w * inv - m.w * m.w, 0.f));

    float p = m.x * m.x + m.y * m.y + m.z * m.z + m.w * m.w
            + sd.x * sd.x + sd.y * sd.y + sd.z * sd.z + sd.w * sd.w;
    p += __shfl_xor(p, 1);
    p += __shfl_xor(p, 2);
    float rn = 1.0f / fmaxf(sqrtf(p), COS_EPS);

    H8 o;
    o.h2[0] = __floats2half2_rn(m.x * rn,  m.y * rn);
    o.h2[1] = __floats2half2_rn(m.z * rn,  m.w * rn);
    o.h2[2] = __floats2half2_rn(sd.x * rn, sd.y * rn);
    o.h2[3] = __floats2half2_rn(sd.z * rn, sd.w * rn);
    feat[gid] = o.f4;             // node-major: ((n*4+b)*4+c4), coalesced
}

// Kernel 2: one WAVE per edge, all 4 batches. Lane l: g=l>>2 member slot,
// q=l&3 chunk. A member gather = 256 contiguous bytes (full lines) covering
// all 4 batches -> every fetched line fully consumed by this wave.
__global__ void edge_sim_kernel(const float4* __restrict__ feat,
                                const int* __restrict__ members,
                                const int* __restrict__ centers,
                                const int* __restrict__ offsets,
                                float* __restrict__ ms) {
    int tid  = blockIdx.x * blockDim.x + threadIdx.x;
    int e    = tid >> 6;
    if (e >= En) return;
    int lane = threadIdx.x & 63;
    int g    = lane >> 2;
    int q    = lane & 3;

    int off0 = offsets[e];
    int off1 = offsets[e + 1];
    int deg  = off1 - off0;
    int cn   = centers[e];

    // center chunks (this lane's q-chunk) for all batches, as floats
    float cf[Bn][8];
#pragma unroll
    for (int b_ = 0; b_ < Bn; ++b_) {
        H8 u; u.f4 = feat[(cn * 4 + b_) * 4 + q];
#pragma unroll
        for (int i = 0; i < 4; ++i) {
            float2 p = __half22float2(u.h2[i]);
            cf[b_][2 * i]     = p.x;
            cf[b_][2 * i + 1] = p.y;
        }
    }

    float sums[Bn] = {0.f, 0.f, 0.f, 0.f};
    for (int m0 = g; m0 < deg; m0 += 16) {
        int mn = members[off0 + m0];
#pragma unroll
        for (int b_ = 0; b_ < Bn; ++b_) {
            H8 u; u.f4 = feat[(mn * 4 + b_) * 4 + q];
            float d = 0.f;
#pragma unroll
            for (int i = 0; i < 4; ++i) {
                float2 p = __half22float2(u.h2[i]);
                d += p.x * cf[b_][2 * i] + p.y * cf[b_][2 * i + 1];
            }
            d += __shfl_xor(d, 1);
            d += __shfl_xor(d, 2);   // all 4 lanes of group g hold full 32-dot
            sums[b_] += fminf(fmaxf(d, 0.f), 1.f);
        }
    }
    // reduce across the 16 groups (strides 4..32); q-copies don't double-count
#pragma unroll
    for (int b_ = 0; b_ < Bn; ++b_) {
        float s = sums[b_];
        s += __shfl_xor(s, 4);
        s += __shfl_xor(s, 8);
        s += __shfl_xor(s, 16);
        s += __shfl_xor(s, 32);
        sums[b_] = s;
    }
    if (lane == 0) {
        float invd = 1.0f / fmaxf((float)deg, 1.0f);
#pragma unroll
        for (int b_ = 0; b_ < Bn; ++b_) ms[b_ * En + e] = sums[b_] * invd;
    }
}

// Kernel 3: per-batch min/max via uint-bit atomics (values >= 0 so uint order
// == float order). 64 blocks per batch, 2 atomics per block (512 total).
__global__ void minmax_kernel(const float* __restrict__ ms, unsigned* __restrict__ mm) {
    int b = blockIdx.x >> 6;
    int j = blockIdx.x & 63;
    const float* p = ms + b * En;
    float lo = INFINITY, hi = 0.f;
    for (int i = j * blockDim.x + threadIdx.x; i < En; i += 64 * 256) {
        float v = p[i];
        lo = fminf(lo, v);
        hi = fmaxf(hi, v);
    }
#pragma unroll
    for (int m = 1; m < 64; m <<= 1) {
        lo = fminf(lo, __shfl_xor(lo, m));
        hi = fmaxf(hi, __shfl_xor(hi, m));
    }
    __shared__ float slo[4], shi[4];
    int wid  = threadIdx.x >> 6;
    int lane = threadIdx.x & 63;
    if (lane == 0) { slo[wid] = lo; shi[wid] = hi; }
    __syncthreads();
    if (threadIdx.x == 0) {
        float flo = fminf(fminf(slo[0], slo[1]), fminf(slo[2], slo[3]));
        float fhi = fmaxf(fmaxf(shi[0], shi[1]), fmaxf(shi[2], shi[3]));
        atomicMin(&mm[b * 2],     __float_as_uint(flo));
        atomicMax(&mm[b * 2 + 1], __float_as_uint(fhi));
    }
}

// Kernel 4: out = W * (1 + LAM * minmax-normed mean_sim)
__global__ void out_kernel(const float* __restrict__ ms, const unsigned* __restrict__ mm,
                           const float* __restrict__ W, float* __restrict__ out) {
    int gid = blockIdx.x * blockDim.x + threadIdx.x;
    if (gid >= Bn * En) return;
    int b = gid / En;
    int e = gid - b * En;
    float smin = __uint_as_float(mm[b * 2]);
    float smax = __uint_as_float(mm[b * 2 + 1]);
    float v = (ms[gid] - smin) * __frcp_rn(smax - smin + NORM_EPS);
    out[gid] = W[e] * (1.0f + LAM * v);
}

extern "C" void kernel_launch(void* const* d_in, const int* in_sizes, int n_in,
                              void* d_out, int out_size, void* d_ws, size_t ws_size,
                              hipStream_t stream) {
    const float* x_raw        = (const float*)d_in[0];
    // d_in[1] = H, unused
    const float* W            = (const float*)d_in[2];
    const int*   edge_members = (const int*)d_in[3];
    const int*   edge_centers = (const int*)d_in[4];
    const int*   edge_offsets = (const int*)d_in[5];
    float*       out          = (float*)d_out;

    float4*   feat = (float4*)d_ws;                                 // N*B*64 B = 12.8 MB
    float*    ms   = (float*)((char*)d_ws + (size_t)Nn * Bn * 64);  // B*E floats
    unsigned* mm   = (unsigned*)(ms + (size_t)Bn * En);             // 2*B uints

    {
        int total = Bn * Nn * 4;
        feat_kernel<<<(total + 255) / 256, 256, 0, stream>>>(x_raw, feat, mm);
    }
    {
        long long threads = (long long)En * 64;           // one wave per edge
        int blocks = (int)((threads + 255) / 256);
        edge_sim_kernel<<<blocks, 256, 0, stream>>>(
            feat, edge_members, edge_centers, edge_offsets, ms);
    }
    minmax_kernel<<<Bn * 64, 256, 0, stream>>>(ms, mm);
    {
        int total = Bn * En;
        out_kernel<<<(total + 255) / 256, 256, 0, stream>>>(ms, mm, W, out);
    }
}

// Round 8
// 75.577 us; speedup vs baseline: 1.3988x; 1.0314x over previous
//
#include <hip/hip_runtime.h>
#include <hip/hip_fp16.h>

#define Bn 4
#define Tn 16
#define Nn 50000
#define Cn 16
#define En 50000
#define LAM 0.3f
#define COS_EPS 1e-8f
#define NORM_EPS 1e-8f

// fp16 feature table, NODE-major: feat[n][b][32] halves -> node row = 256 B,
// fully consumed per member gather by the 4-batch unroll (full-line util).
// Chunk c4 holds [mu4|sd4] (fixed permutation, consistent member & center).
union H8 { __half2 h2[4]; float4 f4; };

// Kernel 1: thread = (n, b, c4); writes 16 B chunks, wave = 1 KB contiguous.
// x reads: per t, each b-group of 16 lanes reads 256 B contiguous. Coalesced.
// Also re-inits the global min/max cells every launch (replay-safe).
__global__ void feat_kernel(const float* __restrict__ x, float4* __restrict__ feat,
                            unsigned* __restrict__ mm) {
    if (blockIdx.x == 0 && threadIdx.x < 2 * Bn) {
        mm[threadIdx.x] = (threadIdx.x & 1) ? 0u : 0x7F800000u;  // min=+inf, max=0
    }
    int gid = blockIdx.x * blockDim.x + threadIdx.x;
    if (gid >= Bn * Nn * 4) return;
    int c4 = gid & 3;
    int b  = (gid >> 2) & 3;
    int n  = gid >> 4;

    const float4* x4 = (const float4*)x;
    float4 s  = make_float4(0.f, 0.f, 0.f, 0.f);
    float4 ss = make_float4(0.f, 0.f, 0.f, 0.f);
    int base = (b * Tn) * Nn;     // row units of 16 floats
#pragma unroll
    for (int t = 0; t < Tn; ++t) {
        float4 v = x4[(base + t * Nn + n) * 4 + c4];
        s.x += v.x; s.y += v.y; s.z += v.z; s.w += v.w;
        ss.x += v.x * v.x; ss.y += v.y * v.y; ss.z += v.z * v.z; ss.w += v.w * v.w;
    }
    const float inv = 1.0f / (float)Tn;
    float4 m, sd;
    m.x = s.x * inv; m.y = s.y * inv; m.z = s.z * inv; m.w = s.w * inv;
    sd.x = sqrtf(fmaxf(ss.x * inv - m.x * m.x, 0.f));
    sd.y = sqrtf(fmaxf(ss.y * inv - m.y * m.y, 0.f));
    sd.z = sqrtf(fmaxf(ss.z * inv - m.z * m.z, 0.f));
    sd.w = sqrtf(fmaxf(ss.w * inv - m.w * m.w, 0.f));

    float p = m.x * m.x + m.y * m.y + m.z * m.z + m.w * m.w
            + sd.x * sd.x + sd.y * sd.y + sd.z * sd.z + sd.w * sd.w;
    p += __shfl_xor(p, 1);
    p += __shfl_xor(p, 2);
    float rn = 1.0f / fmaxf(sqrtf(p), COS_EPS);

    H8 o;
    o.h2[0] = __floats2half2_rn(m.x * rn,  m.y * rn);
    o.h2[1] = __floats2half2_rn(m.z * rn,  m.w * rn);
    o.h2[2] = __floats2half2_rn(sd.x * rn, sd.y * rn);
    o.h2[3] = __floats2half2_rn(sd.z * rn, sd.w * rn);
    feat[gid] = o.f4;             // node-major: ((n*4+b)*4+c4), coalesced
}

// Kernel 2: one WAVE per edge, all 4 batches. Lane l: g=l>>2 member slot,
// q=l&3 chunk. Member gather = 256 contiguous bytes (full lines) per node.
// e is wave-uniform -> forced to SGPR so offsets/centers go through the
// scalar (SMEM) path and issue off the vector critical chain. Center row is
// kept PACKED fp16 (16 VGPRs, not 32) -- converts happen inside the single
// m-iteration anyway (deg=16 -> one trip), so no recompute cost.
__global__ void edge_sim_kernel(const float4* __restrict__ feat,
                                const int* __restrict__ members,
                                const int* __restrict__ centers,
                                const int* __restrict__ offsets,
                                float* __restrict__ ms) {
    int tid  = blockIdx.x * blockDim.x + threadIdx.x;
    int e    = __builtin_amdgcn_readfirstlane(tid >> 6);   // wave-uniform -> SGPR
    if (e >= En) return;                                   // uniform branch
    int lane = threadIdx.x & 63;
    int g    = lane >> 2;
    int q    = lane & 3;

    int off0 = offsets[e];        // s_load
    int off1 = offsets[e + 1];    // s_load
    int deg  = off1 - off0;
    int cn   = centers[e];        // s_load

    // head of the dependent chain: issue member-index load first
    int mn0 = (g < deg) ? members[off0 + g] : -1;

    // center chunks (this lane's q-chunk) for all batches, packed fp16
    H8 cp[Bn];
#pragma unroll
    for (int b_ = 0; b_ < Bn; ++b_) cp[b_].f4 = feat[(cn * 4 + b_) * 4 + q];

    float sums[Bn] = {0.f, 0.f, 0.f, 0.f};
    for (int m0 = g; m0 < deg; m0 += 16) {
        int mn = (m0 == g) ? mn0 : members[off0 + m0];
#pragma unroll
        for (int b_ = 0; b_ < Bn; ++b_) {
            H8 u; u.f4 = feat[(mn * 4 + b_) * 4 + q];
            float d = 0.f;
#pragma unroll
            for (int i = 0; i < 4; ++i) {
                float2 pm = __half22float2(u.h2[i]);
                float2 pc = __half22float2(cp[b_].h2[i]);
                d += pm.x * pc.x + pm.y * pc.y;
            }
            d += __shfl_xor(d, 1);
            d += __shfl_xor(d, 2);   // all 4 lanes of group g hold full 32-dot
            sums[b_] += fminf(fmaxf(d, 0.f), 1.f);
        }
    }
    // reduce across the 16 groups (strides 4..32); q-copies don't double-count
#pragma unroll
    for (int b_ = 0; b_ < Bn; ++b_) {
        float s = sums[b_];
        s += __shfl_xor(s, 4);
        s += __shfl_xor(s, 8);
        s += __shfl_xor(s, 16);
        s += __shfl_xor(s, 32);
        sums[b_] = s;
    }
    if (lane == 0) {
        float invd = 1.0f / fmaxf((float)deg, 1.0f);
#pragma unroll
        for (int b_ = 0; b_ < Bn; ++b_) ms[b_ * En + e] = sums[b_] * invd;
    }
}

// Kernel 3: per-batch min/max via uint-bit atomics (values >= 0 so uint order
// == float order). 64 blocks per batch, 2 atomics per block (512 total).
__global__ void minmax_kernel(const float* __restrict__ ms, unsigned* __restrict__ mm) {
    int b = blockIdx.x >> 6;
    int j = blockIdx.x & 63;
    const float* p = ms + b * En;
    float lo = INFINITY, hi = 0.f;
    for (int i = j * blockDim.x + threadIdx.x; i < En; i += 64 * 256) {
        float v = p[i];
        lo = fminf(lo, v);
        hi = fmaxf(hi, v);
    }
#pragma unroll
    for (int m = 1; m < 64; m <<= 1) {
        lo = fminf(lo, __shfl_xor(lo, m));
        hi = fmaxf(hi, __shfl_xor(hi, m));
    }
    __shared__ float slo[4], shi[4];
    int wid  = threadIdx.x >> 6;
    int lane = threadIdx.x & 63;
    if (lane == 0) { slo[wid] = lo; shi[wid] = hi; }
    __syncthreads();
    if (threadIdx.x == 0) {
        float flo = fminf(fminf(slo[0], slo[1]), fminf(slo[2], slo[3]));
        float fhi = fmaxf(fmaxf(shi[0], shi[1]), fmaxf(shi[2], shi[3]));
        atomicMin(&mm[b * 2],     __float_as_uint(flo));
        atomicMax(&mm[b * 2 + 1], __float_as_uint(fhi));
    }
}

// Kernel 4: out = W * (1 + LAM * minmax-normed mean_sim)
__global__ void out_kernel(const float* __restrict__ ms, const unsigned* __restrict__ mm,
                           const float* __restrict__ W, float* __restrict__ out) {
    int gid = blockIdx.x * blockDim.x + threadIdx.x;
    if (gid >= Bn * En) return;
    int b = gid / En;
    int e = gid - b * En;
    float smin = __uint_as_float(mm[b * 2]);
    float smax = __uint_as_float(mm[b * 2 + 1]);
    float v = (ms[gid] - smin) * __frcp_rn(smax - smin + NORM_EPS);
    out[gid] = W[e] * (1.0f + LAM * v);
}

extern "C" void kernel_launch(void* const* d_in, const int* in_sizes, int n_in,
                              void* d_out, int out_size, void* d_ws, size_t ws_size,
                              hipStream_t stream) {
    const float* x_raw        = (const float*)d_in[0];
    // d_in[1] = H, unused
    const float* W            = (const float*)d_in[2];
    const int*   edge_members = (const int*)d_in[3];
    const int*   edge_centers = (const int*)d_in[4];
    const int*   edge_offsets = (const int*)d_in[5];
    float*       out          = (float*)d_out;

    float4*   feat = (float4*)d_ws;                                 // N*B*64 B = 12.8 MB
    float*    ms   = (float*)((char*)d_ws + (size_t)Nn * Bn * 64);  // B*E floats
    unsigned* mm   = (unsigned*)(ms + (size_t)Bn * En);             // 2*B uints

    {
        int total = Bn * Nn * 4;
        feat_kernel<<<(total + 255) / 256, 256, 0, stream>>>(x_raw, feat, mm);
    }
    {
        long long threads = (long long)En * 64;           // one wave per edge
        int blocks = (int)((threads + 255) / 256);
        edge_sim_kernel<<<blocks, 256, 0, stream>>>(
            feat, edge_members, edge_centers, edge_offsets, ms);
    }
    minmax_kernel<<<Bn * 64, 256, 0, stream>>>(ms, mm);
    {
        int total = Bn * En;
        out_kernel<<<(total + 255) / 256, 256, 0, stream>>>(ms, mm, W, out);
    }
}